// Round 1
// baseline (314.362 us; speedup 1.0000x reference)
//
#include <hip/hip_runtime.h>

#define SPB 4   // samples per block
#define TPB 256

__global__ __launch_bounds__(TPB, 2)
void conv4d_fused(const float* __restrict__ x,
                  const float* __restrict__ w1, const float* __restrict__ b1,
                  const float* __restrict__ w2, const float* __restrict__ b2,
                  float* __restrict__ out, int B)
{
    __shared__ float s_w1[162];
    __shared__ float s_w2[648];
    __shared__ float s_b1[2];
    __shared__ float s_b2[4];
    __shared__ float s_x[SPB * 2401];   // [s][l*343 + d*49 + h*7 + w]
    __shared__ float s_h1[SPB * 1250];  // [s][o*625 + l*125 + d*25 + h*5 + w]

    const int t  = threadIdx.x;
    const int s0 = blockIdx.x * SPB;
    const int ns = min(SPB, B - s0);

    // ---- stage weights + biases
    for (int i = t; i < 162; i += TPB) s_w1[i] = w1[i];
    for (int i = t; i < 648; i += TPB) s_w2[i] = w2[i];
    if (t < 2) s_b1[t] = b1[t];
    if (t < 4) s_b2[t] = b2[t];

    // ---- stage inputs (flat coalesced copy across the block's samples)
    {
        const float* xp = x + (size_t)s0 * 2401;
        const int n = ns * 2401;
        for (int i = t; i < n; i += TPB) s_x[i] = xp[i];
    }
    __syncthreads();

    // ---- conv1 + ReLU: task = (s, o, l, d) -> full 5x5 (h,w) plane in regs
    {
        const int ntask = ns * 50;
        if (t < ntask) {
            int s = t / 50;
            int r = t % 50;
            int o = r / 25; r %= 25;
            int l = r / 5, d = r % 5;

            float acc[5][5];
            const float bias = s_b1[o];
            #pragma unroll
            for (int h = 0; h < 5; ++h)
                #pragma unroll
                for (int w = 0; w < 5; ++w) acc[h][w] = bias;

            const float* xs = s_x + s * 2401;
            const float* wo = s_w1 + o * 81;
            #pragma unroll
            for (int kl = 0; kl < 3; ++kl)
            #pragma unroll
            for (int kd = 0; kd < 3; ++kd) {
                float p[7][7];
                const float* xp = xs + (l + kl) * 343 + (d + kd) * 49;
                #pragma unroll
                for (int i = 0; i < 49; ++i) p[i / 7][i % 7] = xp[i];
                const float* wp = wo + kl * 27 + kd * 9;
                #pragma unroll
                for (int kh = 0; kh < 3; ++kh)
                #pragma unroll
                for (int kw = 0; kw < 3; ++kw) {
                    const float wv = wp[kh * 3 + kw];
                    #pragma unroll
                    for (int h = 0; h < 5; ++h)
                    #pragma unroll
                    for (int w = 0; w < 5; ++w)
                        acc[h][w] += p[h + kh][w + kw] * wv;
                }
            }
            float* hp = s_h1 + s * 1250 + o * 625 + l * 125 + d * 25;
            #pragma unroll
            for (int h = 0; h < 5; ++h)
            #pragma unroll
            for (int w = 0; w < 5; ++w)
                hp[h * 5 + w] = fmaxf(acc[h][w], 0.0f);
        }
    }
    __syncthreads();

    // ---- conv2 + ReLU: task = (s, o2, l, d) -> full 3x3 (h,w) plane in regs
    {
        const int ntask = ns * 36;
        if (t < ntask) {
            int s = t / 36;
            int r = t % 36;
            int o2 = r / 9; r %= 9;
            int l = r / 3, d = r % 3;

            float acc[3][3];
            const float bias = s_b2[o2];
            #pragma unroll
            for (int h = 0; h < 3; ++h)
                #pragma unroll
                for (int w = 0; w < 3; ++w) acc[h][w] = bias;

            #pragma unroll
            for (int c = 0; c < 2; ++c) {
                const float* hs = s_h1 + s * 1250 + c * 625;
                const float* wb = s_w2 + o2 * 162 + c * 81;
                #pragma unroll
                for (int kl = 0; kl < 3; ++kl)
                #pragma unroll
                for (int kd = 0; kd < 3; ++kd) {
                    float p[5][5];
                    const float* pp = hs + (l + kl) * 125 + (d + kd) * 25;
                    #pragma unroll
                    for (int i = 0; i < 25; ++i) p[i / 5][i % 5] = pp[i];
                    const float* wp = wb + kl * 27 + kd * 9;
                    #pragma unroll
                    for (int kh = 0; kh < 3; ++kh)
                    #pragma unroll
                    for (int kw = 0; kw < 3; ++kw) {
                        const float wv = wp[kh * 3 + kw];
                        #pragma unroll
                        for (int h = 0; h < 3; ++h)
                        #pragma unroll
                        for (int w = 0; w < 3; ++w)
                            acc[h][w] += p[h + kh][w + kw] * wv;
                    }
                }
            }
            // task order == output layout order -> near-contiguous block stores
            float* op = out + (size_t)(s0 + s) * 324 + o2 * 81 + l * 27 + d * 9;
            #pragma unroll
            for (int h = 0; h < 3; ++h)
            #pragma unroll
            for (int w = 0; w < 3; ++w)
                op[h * 3 + w] = fmaxf(acc[h][w], 0.0f);
        }
    }
}

extern "C" void kernel_launch(void* const* d_in, const int* in_sizes, int n_in,
                              void* d_out, int out_size, void* d_ws, size_t ws_size,
                              hipStream_t stream)
{
    const float* x  = (const float*)d_in[0];
    const float* w1 = (const float*)d_in[1];
    const float* b1 = (const float*)d_in[2];
    const float* w2 = (const float*)d_in[3];
    const float* b2 = (const float*)d_in[4];
    float* out = (float*)d_out;

    const int B = in_sizes[0] / 2401;        // 16384
    const int grid = (B + SPB - 1) / SPB;    // 4096 blocks
    conv4d_fused<<<grid, TPB, 0, stream>>>(x, w1, b1, w2, b2, out, B);
}